// Round 15
// baseline (58.997 us; speedup 1.0000x reference)
//
#include <hip/hip_runtime.h>

#define BATCH 4
#define NPTS 8192
#define CLOUD_PTS (BATCH * NPTS)        // 32768 points per cloud
#define TOTAL_ROWS (2 * BATCH * NPTS)   // 65536 min-keys (dir0 rows + dir1 rows)

typedef __attribute__((ext_vector_type(8))) short bf16x8;
typedef __attribute__((ext_vector_type(16))) float f32x16;

// Monotone float<->uint key: unsigned ascending == float ascending.
__device__ __forceinline__ unsigned fkey(float f) {
    unsigned u = __float_as_uint(f);
    return (u & 0x80000000u) ? ~u : (u | 0x80000000u);
}
__device__ __forceinline__ float funkey(unsigned k) {
    return (k & 0x80000000u) ? __uint_as_float(k ^ 0x80000000u) : __uint_as_float(~k);
}
__device__ __forceinline__ unsigned short bf16rn(float f) {
    unsigned u = __float_as_uint(f);
    return (unsigned short)((u + 0x7FFFu + ((u >> 16) & 1u)) >> 16);
}
__device__ __forceinline__ float bf2f(unsigned short h) {
    return __uint_as_float(((unsigned)h) << 16);
}

// Feature K-slot pairing (A[k]*B[k] summed by MFMA, K=16 of 32x32x16):
//  k0-2 : (-2p)_h * q_h      k3-5 : (-2p)_l * q_h     k6-8 : (-2p)_h * q_l
//  k9-10: p2_h,p2_l * 1      k11-12: 1 * q2_h,q2_l    k13-15: 0
// => D[m,n] = |p|^2 + |q|^2 - 2 p.q  (drops only (-2p)_l*q_l ~ 2^-18)
// B-side features precomputed once per point; A-side built inline in main.
__global__ __launch_bounds__(256) void prep_kernel(
    const float* __restrict__ tpl, const float* __restrict__ src,
    unsigned short* __restrict__ featB, unsigned int* __restrict__ keys)
{
    const int gid = blockIdx.x * 256 + threadIdx.x;   // 0..65535
    keys[gid] = 0xFFFFFFFFu;

    const int cloud = gid >> 15;                      // 0: tpl, 1: src
    const int idx = gid & (CLOUD_PTS - 1);            // batch*NPTS + pt
    const float* p = (cloud ? src : tpl) + (size_t)idx * 3;
    const float x = p[0], y = p[1], z = p[2];
    const float n2 = fmaf(x, x, fmaf(y, y, z * z));
    const unsigned short n2h = bf16rn(n2);
    const unsigned short n2l = bf16rn(n2 - bf2f(n2h));
    const unsigned short ONE = 0x3F80;

    const unsigned short hx = bf16rn(x), hy = bf16rn(y), hz = bf16rn(z);
    const unsigned short lx = bf16rn(x - bf2f(hx));
    const unsigned short ly = bf16rn(y - bf2f(hy));
    const unsigned short lz = bf16rn(z - bf2f(hz));

    __attribute__((aligned(16))) unsigned short fB[16] = {
        hx, hy, hz, hx, hy, hz, lx, ly, lz, ONE, ONE, n2h, n2l, 0, 0, 0};

    unsigned short* oB = featB + ((size_t)cloud * CLOUD_PTS + idx) * 16;
    *(float4*)&oB[0] = *(float4*)&fB[0];
    *(float4*)&oB[8] = *(float4*)&fB[8];
}

// Main kernel: block = (256 rows of cloud[dir]) x (1024-col chunk of
// cloud[1-dir]) x (batch,dir). Grid (32,8,8) = 2048 blocks; LDS exactly
// 32 KB -> 5 blocks/CU resident (20 waves/CU, +25% TLP vs the 4/CU config)
// to hide MFMA->fmin latency. 4 waves x 64 rows (2 MFMA row-tiles).
// Single staging phase of 1024 cols; inner loop: 1 ds_read_b128 + 2 MFMA +
// 32 independent fmin. Epilogue: XOR-swizzled LDS-transpose (stride 32,
// 2-way bank alias = free), 1 atomic per row per lane.
// 32x32x16 layouts: A row=lane&31, k=(lane>>5)*8+j; B col=lane&31, same k.
// C/D: col=lane&31, row=(r&3)+8*(r>>2)+4*(lane>>5)   [HW-verified mapping]
__global__ __launch_bounds__(256, 5) void chamfer_mfma_kernel(
    const float* __restrict__ tpl, const float* __restrict__ src,
    const unsigned short* __restrict__ featB,
    unsigned int* __restrict__ keys)
{
    // Union LDS, exactly 32 KB: staging (2*1024*8 shorts) / epilogue (4 waves x 64 x 32 f32)
    __shared__ __align__(16) unsigned char smem[32768];
    unsigned short* sB = (unsigned short*)smem;
    float* sEp = (float*)smem;

    const int aSlab = blockIdx.x;        // 0..31 (256 rows)
    const int bChnk = blockIdx.y;        // 0..7  (1024 cols)
    const int dir   = blockIdx.z & 1;    // 0: tpl->src, 1: src->tpl
    const int batch = blockIdx.z >> 1;   // 0..3

    const int t    = threadIdx.x;
    const int w    = t >> 6;             // wave 0..3
    const int lane = t & 63;
    const int col  = lane & 31;
    const int half = lane >> 5;          // k-half (k0-7 / k8-15)

    const float* Araw = (dir ? src : tpl) + (size_t)batch * NPTS * 3;
    const unsigned short* Bf =
        featB + ((size_t)((1 - dir) * CLOUD_PTS + batch * NPTS + bChnk * 1024)) * 16;

    const short ONE = (short)0x3F80;     // bf16 1.0

    // This wave's 2 A-fragments built inline from raw floats (2 points/lane).
    bf16x8 afr[2];
#pragma unroll
    for (int a = 0; a < 2; ++a) {
        const float* p = Araw + (size_t)(aSlab * 256 + w * 64 + a * 32 + col) * 3;
        const float x = p[0], y = p[1], z = p[2];
        const float n2 = fmaf(x, x, fmaf(y, y, z * z));
        const unsigned short n2h = bf16rn(n2);
        const unsigned short n2l = bf16rn(n2 - bf2f(n2h));
        const float mx = -2.0f * x, my = -2.0f * y, mz = -2.0f * z;
        const unsigned short ahx = bf16rn(mx), ahy = bf16rn(my), ahz = bf16rn(mz);
        const unsigned short alx = bf16rn(mx - bf2f(ahx));
        const unsigned short aly = bf16rn(my - bf2f(ahy));
        const unsigned short alz = bf16rn(mz - bf2f(ahz));
        const bf16x8 f0 = {(short)ahx, (short)ahy, (short)ahz, (short)alx,
                           (short)aly, (short)alz, (short)ahx, (short)ahy};
        const bf16x8 f1 = {(short)ahz, (short)n2h, (short)n2l, ONE, ONE, 0, 0, 0};
        afr[a] = half ? f1 : f0;
    }

    float vmin[2][16];
#pragma unroll
    for (int a = 0; a < 2; ++a)
#pragma unroll
        for (int r = 0; r < 16; ++r) vmin[a][r] = 3.0e38f;

    const f32x16 ZERO = (f32x16)(0.0f);

    // Single staging phase: 1024 cols x 32 B = 2048 float4s, 8 per thread.
    {
        const float4* gB = (const float4*)Bf;
#pragma unroll
        for (int i = 0; i < 8; ++i) {
            const int c = t + i * 256;          // float4 index, 0..2047
            const int pt = c >> 1, h = c & 1;
            *(float4*)&sB[((size_t)(h * 1024 + pt)) * 8] = gB[c];
        }
    }
    __syncthreads();

    const unsigned short* sBh = &sB[(size_t)(half * 1024) * 8];
#pragma unroll 8
    for (int bt = 0; bt < 32; ++bt) {
        const bf16x8 bfr = *(const bf16x8*)&sBh[((size_t)(bt * 32 + col)) * 8];
#pragma unroll
        for (int a = 0; a < 2; ++a) {
            const f32x16 d = __builtin_amdgcn_mfma_f32_32x32x16_bf16(afr[a], bfr, ZERO, 0, 0, 0);
#pragma unroll
            for (int r = 0; r < 16; ++r) vmin[a][r] = fminf(vmin[a][r], d[r]);
        }
    }
    __syncthreads();   // all waves done with sB before epilogue reuse

    // Epilogue: XOR-swizzled LDS-transpose fold. Per-wave region: 64 rows x
    // 32 f32, element idx stored at [wl*32 + (idx ^ (wl&31))].
    float* ep = sEp + (size_t)w * (64 * 32);
#pragma unroll
    for (int a = 0; a < 2; ++a)
#pragma unroll
        for (int r = 0; r < 16; ++r) {
            const int idx = a * 16 + r;
            ep[lane * 32 + (idx ^ (lane & 31))] = vmin[a][r];
        }
    __syncthreads();

    // Lane owns row R = lane (within this wave's 64 rows). Source partials
    // live in the 32 writer-lanes wl = hsrc*32 + c, element elem = a_*16+r_.
    const int a_   = lane >> 5;
    const int rit  = lane & 31;
    const int hsrc = (rit >> 2) & 1;
    const int r_   = (rit & 3) | (((rit >> 3) & 3) << 2);
    const int elem = a_ * 16 + r_;
    const float* epw = ep + (size_t)(hsrc * 32) * 32;

    float m = 3.0e38f;
#pragma unroll
    for (int c = 0; c < 32; ++c)
        m = fminf(m, epw[c * 32 + (elem ^ c)]);

    unsigned int* rowKey = keys + dir * CLOUD_PTS + batch * NPTS;
    atomicMin(&rowKey[aSlab * 256 + w * 64 + lane], fkey(m));
}

// Decode key, sqrt(max(d2,1e-12)), per-block deterministic sums.
__global__ __launch_bounds__(256) void reduce_rows_kernel(
    const unsigned int* __restrict__ minkey, float* __restrict__ blockSums)
{
    const int gid = blockIdx.x * 256 + threadIdx.x;
    const float v = funkey(minkey[gid]);
    float d = sqrtf(fmaxf(v, 1e-12f));
#pragma unroll
    for (int off = 32; off; off >>= 1) d += __shfl_down(d, off);
    __shared__ float wsum[4];
    const int wave = threadIdx.x >> 6, lane = threadIdx.x & 63;
    if (lane == 0) wsum[wave] = d;
    __syncthreads();
    if (threadIdx.x == 0)
        blockSums[blockIdx.x] = (wsum[0] + wsum[1]) + (wsum[2] + wsum[3]);
}

__global__ __launch_bounds__(256) void final_kernel(
    const float* __restrict__ blockSums, float* __restrict__ out)
{
    float d = blockSums[threadIdx.x];
#pragma unroll
    for (int off = 32; off; off >>= 1) d += __shfl_down(d, off);
    __shared__ float wsum[4];
    const int wave = threadIdx.x >> 6, lane = threadIdx.x & 63;
    if (lane == 0) wsum[wave] = d;
    __syncthreads();
    if (threadIdx.x == 0) {
        const float total = (wsum[0] + wsum[1]) + (wsum[2] + wsum[3]);
        out[0] = total / (float)(BATCH * NPTS);
    }
}

extern "C" void kernel_launch(void* const* d_in, const int* in_sizes, int n_in,
                              void* d_out, int out_size, void* d_ws, size_t ws_size,
                              hipStream_t stream) {
    const float* tpl = (const float*)d_in[0];
    const float* src = (const float*)d_in[1];
    float* out = (float*)d_out;

    unsigned short* featB = (unsigned short*)d_ws;                        // 2 MB
    unsigned int* keys    = (unsigned int*)((char*)d_ws + 2u * 1024 * 1024); // 256 KB
    float* blockSums      = (float*)(keys + TOTAL_ROWS);

    prep_kernel<<<TOTAL_ROWS / 256, 256, 0, stream>>>(tpl, src, featB, keys);

    dim3 grid(NPTS / 256, NPTS / 1024, 2 * BATCH);   // (32, 8, 8) = 2048 blocks
    chamfer_mfma_kernel<<<grid, 256, 0, stream>>>(tpl, src, featB, keys);

    reduce_rows_kernel<<<TOTAL_ROWS / 256, 256, 0, stream>>>(keys, blockSums);
    final_kernel<<<1, 256, 0, stream>>>(blockSums, out);
}

// Round 16
// 31.067 us; speedup vs baseline: 1.8990x; 1.8990x over previous
//
#include <hip/hip_runtime.h>

#define BATCH 4
#define NPTS 8192
#define CLOUD_PTS (BATCH * NPTS)        // 32768 points per cloud
#define TOTAL_ROWS (2 * BATCH * NPTS)   // 65536 min-keys (dir0 rows + dir1 rows)

typedef __attribute__((ext_vector_type(8))) short bf16x8;
typedef __attribute__((ext_vector_type(16))) float f32x16;

// Monotone float<->uint key: unsigned ascending == float ascending.
__device__ __forceinline__ unsigned fkey(float f) {
    unsigned u = __float_as_uint(f);
    return (u & 0x80000000u) ? ~u : (u | 0x80000000u);
}
__device__ __forceinline__ float funkey(unsigned k) {
    return (k & 0x80000000u) ? __uint_as_float(k ^ 0x80000000u) : __uint_as_float(~k);
}
__device__ __forceinline__ unsigned short bf16rn(float f) {
    unsigned u = __float_as_uint(f);
    return (unsigned short)((u + 0x7FFFu + ((u >> 16) & 1u)) >> 16);
}
__device__ __forceinline__ float bf2f(unsigned short h) {
    return __uint_as_float(((unsigned)h) << 16);
}

// Feature K-slot pairing (A[k]*B[k] summed by MFMA, K=16 of 32x32x16):
//  k0-2 : (-2p)_h * q_h      k3-5 : (-2p)_l * q_h     k6-8 : (-2p)_h * q_l
//  k9-10: p2_h,p2_l * 1      k11-12: 1 * q2_h,q2_l    k13-15: 0
// => D[m,n] = |p|^2 + |q|^2 - 2 p.q  (drops only (-2p)_l*q_l ~ 2^-18)
__global__ __launch_bounds__(256) void prep_kernel(
    const float* __restrict__ tpl, const float* __restrict__ src,
    unsigned short* __restrict__ featA, unsigned short* __restrict__ featB,
    unsigned int* __restrict__ keys)
{
    const int gid = blockIdx.x * 256 + threadIdx.x;   // 0..65535
    keys[gid] = 0xFFFFFFFFu;

    const int cloud = gid >> 15;                      // 0: tpl, 1: src
    const int idx = gid & (CLOUD_PTS - 1);            // batch*NPTS + pt
    const float* p = (cloud ? src : tpl) + (size_t)idx * 3;
    const float x = p[0], y = p[1], z = p[2];
    const float n2 = fmaf(x, x, fmaf(y, y, z * z));
    const unsigned short n2h = bf16rn(n2);
    const unsigned short n2l = bf16rn(n2 - bf2f(n2h));
    const unsigned short ONE = 0x3F80;

    const unsigned short hx = bf16rn(x), hy = bf16rn(y), hz = bf16rn(z);
    const unsigned short lx = bf16rn(x - bf2f(hx));
    const unsigned short ly = bf16rn(y - bf2f(hy));
    const unsigned short lz = bf16rn(z - bf2f(hz));
    const float mx = -2.0f * x, my = -2.0f * y, mz = -2.0f * z;
    const unsigned short ahx = bf16rn(mx), ahy = bf16rn(my), ahz = bf16rn(mz);
    const unsigned short alx = bf16rn(mx - bf2f(ahx));
    const unsigned short aly = bf16rn(my - bf2f(ahy));
    const unsigned short alz = bf16rn(mz - bf2f(ahz));

    __attribute__((aligned(16))) unsigned short fA[16] = {
        ahx, ahy, ahz, alx, aly, alz, ahx, ahy, ahz, n2h, n2l, ONE, ONE, 0, 0, 0};
    __attribute__((aligned(16))) unsigned short fB[16] = {
        hx, hy, hz, hx, hy, hz, lx, ly, lz, ONE, ONE, n2h, n2l, 0, 0, 0};

    unsigned short* oA = featA + ((size_t)cloud * CLOUD_PTS + idx) * 16;
    unsigned short* oB = featB + ((size_t)cloud * CLOUD_PTS + idx) * 16;
    *(float4*)&oA[0] = *(float4*)&fA[0];
    *(float4*)&oA[8] = *(float4*)&fA[8];
    *(float4*)&oB[0] = *(float4*)&fB[0];
    *(float4*)&oB[8] = *(float4*)&fB[8];
}

// Main kernel: block = (256 rows of cloud[dir]) x (2048-col chunk of
// cloud[1-dir]) x (batch,dir). Grid (32,4,8) = 1024 blocks = 4/CU exactly.
// 4 waves x 64 rows (2 MFMA row-tiles). Cols staged in 2 phases of 1024
// (32 KB LDS). Inner loop: 1 ds_read_b128 + 2 MFMA + 32 independent fmin.
// Epilogue: LDS-transpose fold (no shuffles), 1 atomic per row per lane.
// NOTE (ledger): 4-chain ILP, fused prep, plain-store partials, threadfence
// tail-fusion, asm min3, paired fminf, 1-WG tail, inline-A, and 5/CU
// launch_bounds ALL regressed or were neutral vs this exact structure.
// The 2-chain body needs ~64 VGPR; tighter launch_bounds spills (R6/R11/R15).
// 32x32x16 layouts: A row=lane&31, k=(lane>>5)*8+j; B col=lane&31, same k.
// C/D: col=lane&31, row=(r&3)+8*(r>>2)+4*(lane>>5)   [HW-verified mapping]
__global__ __launch_bounds__(256, 4) void chamfer_mfma_kernel(
    const unsigned short* __restrict__ featA,
    const unsigned short* __restrict__ featB,
    unsigned int* __restrict__ keys)
{
    // Union LDS: staging (2*1024*8 shorts = 32 KB) / epilogue (4 waves x 64 x 33 f32)
    __shared__ __align__(16) unsigned char smem[4 * 64 * 33 * 4];
    unsigned short* sB = (unsigned short*)smem;
    float* sEp = (float*)smem;

    const int aSlab = blockIdx.x;        // 0..31 (256 rows)
    const int bChnk = blockIdx.y;        // 0..3  (2048 cols)
    const int dir   = blockIdx.z & 1;    // 0: tpl->src, 1: src->tpl
    const int batch = blockIdx.z >> 1;   // 0..3

    const int t    = threadIdx.x;
    const int w    = t >> 6;             // wave 0..3
    const int lane = t & 63;
    const int col  = lane & 31;
    const int half = lane >> 5;          // k-half (k0-7 / k8-15)

    const unsigned short* Af =
        featA + ((size_t)(dir * CLOUD_PTS + batch * NPTS + aSlab * 256)) * 16;
    const unsigned short* Bf =
        featB + ((size_t)((1 - dir) * CLOUD_PTS + batch * NPTS + bChnk * 2048)) * 16;

    // This wave's 2 A-fragments (64 rows), straight from global (L2-resident).
    bf16x8 afr[2];
#pragma unroll
    for (int a = 0; a < 2; ++a)
        afr[a] = *(const bf16x8*)(Af + ((size_t)(w * 64 + a * 32 + col)) * 16 + half * 8);

    float vmin[2][16];
#pragma unroll
    for (int a = 0; a < 2; ++a)
#pragma unroll
        for (int r = 0; r < 16; ++r) vmin[a][r] = 3.0e38f;

    const f32x16 ZERO = (f32x16)(0.0f);

    // Two staging phases of 1024 cols each.
#pragma unroll 1
    for (int phase = 0; phase < 2; ++phase) {
        const float4* gB = (const float4*)(Bf + (size_t)phase * 1024 * 16);
#pragma unroll
        for (int i = 0; i < 8; ++i) {
            const int c = t + i * 256;          // float4 index, 0..2047
            const int pt = c >> 1, h = c & 1;
            *(float4*)&sB[((size_t)(h * 1024 + pt)) * 8] = gB[c];
        }
        __syncthreads();

        const unsigned short* sBh = &sB[(size_t)(half * 1024) * 8];
#pragma unroll 8
        for (int bt = 0; bt < 32; ++bt) {
            const bf16x8 bfr = *(const bf16x8*)&sBh[((size_t)(bt * 32 + col)) * 8];
#pragma unroll
            for (int a = 0; a < 2; ++a) {
                const f32x16 d = __builtin_amdgcn_mfma_f32_32x32x16_bf16(afr[a], bfr, ZERO, 0, 0, 0);
#pragma unroll
                for (int r = 0; r < 16; ++r) vmin[a][r] = fminf(vmin[a][r], d[r]);
            }
        }
        __syncthreads();   // all waves done with sB before restage / epilogue reuse
    }

    // Epilogue: LDS-transpose fold. Region per wave: 64 lanes x 33 floats (pad).
    float* ep = sEp + (size_t)w * (64 * 33);
#pragma unroll
    for (int a = 0; a < 2; ++a)
#pragma unroll
        for (int r = 0; r < 16; ++r)
            ep[lane * 33 + a * 16 + r] = vmin[a][r];
    __syncthreads();

    // Lane owns row R = lane (within this wave's 64 rows).
    const int a_   = lane >> 5;
    const int rit  = lane & 31;
    const int hsrc = (rit >> 2) & 1;
    const int r_   = (rit & 3) | (((rit >> 3) & 3) << 2);
    const float* src0 = ep + (size_t)(hsrc * 32) * 33 + (a_ * 16 + r_);

    float m = 3.0e38f;
#pragma unroll
    for (int c = 0; c < 32; ++c)
        m = fminf(m, src0[c * 33]);

    unsigned int* rowKey = keys + dir * CLOUD_PTS + batch * NPTS;
    atomicMin(&rowKey[aSlab * 256 + w * 64 + lane], fkey(m));
}

// Decode key, sqrt(max(d2,1e-12)), per-block deterministic sums.
__global__ __launch_bounds__(256) void reduce_rows_kernel(
    const unsigned int* __restrict__ minkey, float* __restrict__ blockSums)
{
    const int gid = blockIdx.x * 256 + threadIdx.x;
    const float v = funkey(minkey[gid]);
    float d = sqrtf(fmaxf(v, 1e-12f));
#pragma unroll
    for (int off = 32; off; off >>= 1) d += __shfl_down(d, off);
    __shared__ float wsum[4];
    const int wave = threadIdx.x >> 6, lane = threadIdx.x & 63;
    if (lane == 0) wsum[wave] = d;
    __syncthreads();
    if (threadIdx.x == 0)
        blockSums[blockIdx.x] = (wsum[0] + wsum[1]) + (wsum[2] + wsum[3]);
}

__global__ __launch_bounds__(256) void final_kernel(
    const float* __restrict__ blockSums, float* __restrict__ out)
{
    float d = blockSums[threadIdx.x];
#pragma unroll
    for (int off = 32; off; off >>= 1) d += __shfl_down(d, off);
    __shared__ float wsum[4];
    const int wave = threadIdx.x >> 6, lane = threadIdx.x & 63;
    if (lane == 0) wsum[wave] = d;
    __syncthreads();
    if (threadIdx.x == 0) {
        const float total = (wsum[0] + wsum[1]) + (wsum[2] + wsum[3]);
        out[0] = total / (float)(BATCH * NPTS);
    }
}

extern "C" void kernel_launch(void* const* d_in, const int* in_sizes, int n_in,
                              void* d_out, int out_size, void* d_ws, size_t ws_size,
                              hipStream_t stream) {
    const float* tpl = (const float*)d_in[0];
    const float* src = (const float*)d_in[1];
    float* out = (float*)d_out;

    unsigned short* featA = (unsigned short*)d_ws;                        // 2 MB
    unsigned short* featB = featA + (size_t)2 * CLOUD_PTS * 16;           // 2 MB
    unsigned int* keys    = (unsigned int*)((char*)d_ws + 4u * 1024 * 1024); // 256 KB
    float* blockSums      = (float*)(keys + TOTAL_ROWS);

    prep_kernel<<<TOTAL_ROWS / 256, 256, 0, stream>>>(tpl, src, featA, featB, keys);

    dim3 grid(NPTS / 256, NPTS / 2048, 2 * BATCH);   // (32, 4, 8) = 1024 blocks
    chamfer_mfma_kernel<<<grid, 256, 0, stream>>>(featA, featB, keys);

    reduce_rows_kernel<<<TOTAL_ROWS / 256, 256, 0, stream>>>(keys, blockSums);
    final_kernel<<<1, 256, 0, stream>>>(blockSums, out);
}

// Round 17
// 30.558 us; speedup vs baseline: 1.9307x; 1.0167x over previous
//
#include <hip/hip_runtime.h>

#define BATCH 4
#define NPTS 8192
#define CLOUD_PTS (BATCH * NPTS)        // 32768 points per cloud
#define TOTAL_ROWS (2 * BATCH * NPTS)   // 65536 min-keys (dir0 rows + dir1 rows)

typedef __attribute__((ext_vector_type(8))) short bf16x8;
typedef __attribute__((ext_vector_type(16))) float f32x16;

// Monotone float<->uint key: unsigned ascending == float ascending.
__device__ __forceinline__ unsigned fkey(float f) {
    unsigned u = __float_as_uint(f);
    return (u & 0x80000000u) ? ~u : (u | 0x80000000u);
}
__device__ __forceinline__ float funkey(unsigned k) {
    return (k & 0x80000000u) ? __uint_as_float(k ^ 0x80000000u) : __uint_as_float(~k);
}
__device__ __forceinline__ unsigned short bf16rn(float f) {
    unsigned u = __float_as_uint(f);
    return (unsigned short)((u + 0x7FFFu + ((u >> 16) & 1u)) >> 16);
}
__device__ __forceinline__ float bf2f(unsigned short h) {
    return __uint_as_float(((unsigned)h) << 16);
}

// Feature K-slot pairing (A[k]*B[k] summed by MFMA, K=16 of 32x32x16):
//  k0-2 : (-2p)_h * q_h      k3-5 : (-2p)_l * q_h     k6-8 : (-2p)_h * q_l
//  k9-10: p2_h,p2_l * 1      k11-12: 1 * q2_h,q2_l    k13-15: 0
// => D[m,n] = |p|^2 + |q|^2 - 2 p.q  (drops only (-2p)_l*q_l ~ 2^-18)
__global__ __launch_bounds__(256) void prep_kernel(
    const float* __restrict__ tpl, const float* __restrict__ src,
    unsigned short* __restrict__ featA, unsigned short* __restrict__ featB,
    unsigned int* __restrict__ keys)
{
    const int gid = blockIdx.x * 256 + threadIdx.x;   // 0..65535
    keys[gid] = 0xFFFFFFFFu;

    const int cloud = gid >> 15;                      // 0: tpl, 1: src
    const int idx = gid & (CLOUD_PTS - 1);            // batch*NPTS + pt
    const float* p = (cloud ? src : tpl) + (size_t)idx * 3;
    const float x = p[0], y = p[1], z = p[2];
    const float n2 = fmaf(x, x, fmaf(y, y, z * z));
    const unsigned short n2h = bf16rn(n2);
    const unsigned short n2l = bf16rn(n2 - bf2f(n2h));
    const unsigned short ONE = 0x3F80;

    const unsigned short hx = bf16rn(x), hy = bf16rn(y), hz = bf16rn(z);
    const unsigned short lx = bf16rn(x - bf2f(hx));
    const unsigned short ly = bf16rn(y - bf2f(hy));
    const unsigned short lz = bf16rn(z - bf2f(hz));
    const float mx = -2.0f * x, my = -2.0f * y, mz = -2.0f * z;
    const unsigned short ahx = bf16rn(mx), ahy = bf16rn(my), ahz = bf16rn(mz);
    const unsigned short alx = bf16rn(mx - bf2f(ahx));
    const unsigned short aly = bf16rn(my - bf2f(ahy));
    const unsigned short alz = bf16rn(mz - bf2f(ahz));

    __attribute__((aligned(16))) unsigned short fA[16] = {
        ahx, ahy, ahz, alx, aly, alz, ahx, ahy, ahz, n2h, n2l, ONE, ONE, 0, 0, 0};
    __attribute__((aligned(16))) unsigned short fB[16] = {
        hx, hy, hz, hx, hy, hz, lx, ly, lz, ONE, ONE, n2h, n2l, 0, 0, 0};

    unsigned short* oA = featA + ((size_t)cloud * CLOUD_PTS + idx) * 16;
    unsigned short* oB = featB + ((size_t)cloud * CLOUD_PTS + idx) * 16;
    *(float4*)&oA[0] = *(float4*)&fA[0];
    *(float4*)&oA[8] = *(float4*)&fA[8];
    *(float4*)&oB[0] = *(float4*)&fB[0];
    *(float4*)&oB[8] = *(float4*)&fB[8];
}

// Main kernel: block = (256 rows of cloud[dir]) x (2048-col chunk of
// cloud[1-dir]) x (batch,dir). Grid (32,4,8) = 1024 blocks = 4/CU exactly.
// 4 waves x 64 rows (2 MFMA row-tiles). Cols staged in 2 phases of 1024
// (32 KB LDS) via ASYNC global_load_lds (no VGPR round-trip; LDS slot
// s = i*256+t linear, global source index pre-swizzled c = ((s&1023)<<1)|(s>>10)
// so LDS contents are bit-identical to the ds_write version).
// Inner loop: 1 ds_read_b128 + 2 MFMA + 32 independent fmin.
// Epilogue: LDS-transpose fold (no shuffles), 1 atomic per row per lane.
// NOTE (ledger): 4-chain ILP, fused prep, plain-store partials, threadfence
// tail-fusion, asm min3, paired fminf, 1-WG tail, inline-A, and 5/CU
// launch_bounds ALL regressed or were neutral vs this structure.
// The 2-chain body needs ~64 VGPR; tighter launch_bounds spills (R6/R11/R15).
// 32x32x16 layouts: A row=lane&31, k=(lane>>5)*8+j; B col=lane&31, same k.
// C/D: col=lane&31, row=(r&3)+8*(r>>2)+4*(lane>>5)   [HW-verified mapping]
__global__ __launch_bounds__(256, 4) void chamfer_mfma_kernel(
    const unsigned short* __restrict__ featA,
    const unsigned short* __restrict__ featB,
    unsigned int* __restrict__ keys)
{
    // Union LDS: staging (2*1024*8 shorts = 32 KB) / epilogue (4 waves x 64 x 33 f32)
    __shared__ __align__(16) unsigned char smem[4 * 64 * 33 * 4];
    unsigned short* sB = (unsigned short*)smem;
    float* sEp = (float*)smem;

    const int aSlab = blockIdx.x;        // 0..31 (256 rows)
    const int bChnk = blockIdx.y;        // 0..3  (2048 cols)
    const int dir   = blockIdx.z & 1;    // 0: tpl->src, 1: src->tpl
    const int batch = blockIdx.z >> 1;   // 0..3

    const int t    = threadIdx.x;
    const int w    = t >> 6;             // wave 0..3
    const int lane = t & 63;
    const int col  = lane & 31;
    const int half = lane >> 5;          // k-half (k0-7 / k8-15)

    const unsigned short* Af =
        featA + ((size_t)(dir * CLOUD_PTS + batch * NPTS + aSlab * 256)) * 16;
    const unsigned short* Bf =
        featB + ((size_t)((1 - dir) * CLOUD_PTS + batch * NPTS + bChnk * 2048)) * 16;

    // This wave's 2 A-fragments (64 rows), straight from global (L2-resident).
    bf16x8 afr[2];
#pragma unroll
    for (int a = 0; a < 2; ++a)
        afr[a] = *(const bf16x8*)(Af + ((size_t)(w * 64 + a * 32 + col)) * 16 + half * 8);

    float vmin[2][16];
#pragma unroll
    for (int a = 0; a < 2; ++a)
#pragma unroll
        for (int r = 0; r < 16; ++r) vmin[a][r] = 3.0e38f;

    const f32x16 ZERO = (f32x16)(0.0f);

    // Two staging phases of 1024 cols each.
#pragma unroll 1
    for (int phase = 0; phase < 2; ++phase) {
        const float4* gB = (const float4*)(Bf + (size_t)phase * 1024 * 16);
        // Async global->LDS: lane writes LDS slot s = i*256 + t (linear per
        // wave: base + lane*16, as HW requires); global float4 index
        // c = ((s&1023)<<1)|(s>>10) reproduces the [half][pt] layout exactly.
#pragma unroll
        for (int i = 0; i < 8; ++i) {
            const int s = i * 256 + t;
            const int c = ((s & 1023) << 1) | (s >> 10);
            __builtin_amdgcn_global_load_lds(
                (const __attribute__((address_space(1))) unsigned int*)(gB + c),
                (__attribute__((address_space(3))) unsigned int*)(smem + (size_t)s * 16),
                16, 0, 0);
        }
        __syncthreads();   // drains vmcnt (compiler emits waitcnt before barrier)

        const unsigned short* sBh = &sB[(size_t)(half * 1024) * 8];
#pragma unroll 8
        for (int bt = 0; bt < 32; ++bt) {
            const bf16x8 bfr = *(const bf16x8*)&sBh[((size_t)(bt * 32 + col)) * 8];
#pragma unroll
            for (int a = 0; a < 2; ++a) {
                const f32x16 d = __builtin_amdgcn_mfma_f32_32x32x16_bf16(afr[a], bfr, ZERO, 0, 0, 0);
#pragma unroll
                for (int r = 0; r < 16; ++r) vmin[a][r] = fminf(vmin[a][r], d[r]);
            }
        }
        __syncthreads();   // all waves done with sB before restage / epilogue reuse
    }

    // Epilogue: LDS-transpose fold. Region per wave: 64 lanes x 33 floats (pad).
    float* ep = sEp + (size_t)w * (64 * 33);
#pragma unroll
    for (int a = 0; a < 2; ++a)
#pragma unroll
        for (int r = 0; r < 16; ++r)
            ep[lane * 33 + a * 16 + r] = vmin[a][r];
    __syncthreads();

    // Lane owns row R = lane (within this wave's 64 rows).
    const int a_   = lane >> 5;
    const int rit  = lane & 31;
    const int hsrc = (rit >> 2) & 1;
    const int r_   = (rit & 3) | (((rit >> 3) & 3) << 2);
    const float* src0 = ep + (size_t)(hsrc * 32) * 33 + (a_ * 16 + r_);

    float m = 3.0e38f;
#pragma unroll
    for (int c = 0; c < 32; ++c)
        m = fminf(m, src0[c * 33]);

    unsigned int* rowKey = keys + dir * CLOUD_PTS + batch * NPTS;
    atomicMin(&rowKey[aSlab * 256 + w * 64 + lane], fkey(m));
}

// Decode key, sqrt(max(d2,1e-12)), per-block deterministic sums.
__global__ __launch_bounds__(256) void reduce_rows_kernel(
    const unsigned int* __restrict__ minkey, float* __restrict__ blockSums)
{
    const int gid = blockIdx.x * 256 + threadIdx.x;
    const float v = funkey(minkey[gid]);
    float d = sqrtf(fmaxf(v, 1e-12f));
#pragma unroll
    for (int off = 32; off; off >>= 1) d += __shfl_down(d, off);
    __shared__ float wsum[4];
    const int wave = threadIdx.x >> 6, lane = threadIdx.x & 63;
    if (lane == 0) wsum[wave] = d;
    __syncthreads();
    if (threadIdx.x == 0)
        blockSums[blockIdx.x] = (wsum[0] + wsum[1]) + (wsum[2] + wsum[3]);
}

__global__ __launch_bounds__(256) void final_kernel(
    const float* __restrict__ blockSums, float* __restrict__ out)
{
    float d = blockSums[threadIdx.x];
#pragma unroll
    for (int off = 32; off; off >>= 1) d += __shfl_down(d, off);
    __shared__ float wsum[4];
    const int wave = threadIdx.x >> 6, lane = threadIdx.x & 63;
    if (lane == 0) wsum[wave] = d;
    __syncthreads();
    if (threadIdx.x == 0) {
        const float total = (wsum[0] + wsum[1]) + (wsum[2] + wsum[3]);
        out[0] = total / (float)(BATCH * NPTS);
    }
}

extern "C" void kernel_launch(void* const* d_in, const int* in_sizes, int n_in,
                              void* d_out, int out_size, void* d_ws, size_t ws_size,
                              hipStream_t stream) {
    const float* tpl = (const float*)d_in[0];
    const float* src = (const float*)d_in[1];
    float* out = (float*)d_out;

    unsigned short* featA = (unsigned short*)d_ws;                        // 2 MB
    unsigned short* featB = featA + (size_t)2 * CLOUD_PTS * 16;           // 2 MB
    unsigned int* keys    = (unsigned int*)((char*)d_ws + 4u * 1024 * 1024); // 256 KB
    float* blockSums      = (float*)(keys + TOTAL_ROWS);

    prep_kernel<<<TOTAL_ROWS / 256, 256, 0, stream>>>(tpl, src, featA, featB, keys);

    dim3 grid(NPTS / 256, NPTS / 2048, 2 * BATCH);   // (32, 4, 8) = 1024 blocks
    chamfer_mfma_kernel<<<grid, 256, 0, stream>>>(featA, featB, keys);

    reduce_rows_kernel<<<TOTAL_ROWS / 256, 256, 0, stream>>>(keys, blockSums);
    final_kernel<<<1, 256, 0, stream>>>(blockSums, out);
}